// Round 6
// baseline (499.697 us; speedup 1.0000x reference)
//
#include <hip/hip_runtime.h>
#include <math.h>

#define NN 50000
#define NE 500000
#define NREL 4
#define D 128
#define RSZ 512                 // dst-range size (one bin)
#define NRANGE 98               // ceil(NN/512)
#define NBK (NREL * NRANGE)     // 392 sort blocks
#define BCAP 6144               // per-(range,rel) csr capacity (mean 5120, +14 sigma)
#define NCH 128                 // edge chunks per relation
#define CH 3907                 // edges per chunk (128*3907 >= 500000)
#define FCAP 96                 // frag capacity per (chunk,bin): mean 40, +9 sigma
#define CAST_BLKS 6250          // NN*D/4/256
static constexpr float BN_EPS = 1e-5f;

typedef __attribute__((ext_vector_type(8))) short short8;
typedef __attribute__((ext_vector_type(4))) float f32x4;

__device__ __forceinline__ float bf2f(unsigned short u) {
    return __uint_as_float(((unsigned)u) << 16);
}
__device__ __forceinline__ unsigned short f2bf(float f) {  // RTNE
    unsigned x = __float_as_uint(f);
    return (unsigned short)((x + 0x7FFFu + ((x >> 16) & 1u)) >> 16);
}

// ---------------- fused prologue: cast x->bf16, weight transpose+cast, bias sums, bnsum zero ----
__global__ __launch_bounds__(256) void k_pre(const float* __restrict__ x,
                                             const float* __restrict__ W1, const float* __restrict__ W2,
                                             const float* __restrict__ l1W, const float* __restrict__ b1,
                                             const float* __restrict__ b2,
                                             unsigned short* __restrict__ xb,
                                             unsigned short* __restrict__ Wt1,
                                             unsigned short* __restrict__ Wt2,
                                             unsigned short* __restrict__ Wt3,
                                             float* __restrict__ bs1, float* __restrict__ bs2,
                                             float* __restrict__ bnsum) {
    int blk = blockIdx.x, tid = threadIdx.x;
    if (blk < CAST_BLKS) {
        int i = blk * 256 + tid;
        float4 v = *(const float4*)(x + (size_t)i * 4);
        unsigned short u[4] = {f2bf(v.x), f2bf(v.y), f2bf(v.z), f2bf(v.w)};
        *(ushort4*)(xb + (size_t)i * 4) = *(ushort4*)u;
    } else if (blk < CAST_BLKS + 256) {
        int i = (blk - CAST_BLKS) * 256 + tid;  // [0, 65536)
        int kk = i & 511, n = i >> 9;           // coalesced stores along kk
        Wt1[n * 512 + kk] = f2bf(W1[kk * 128 + n]);
        Wt2[n * 512 + kk] = f2bf(W2[kk * 128 + n]);
    } else if (blk < CAST_BLKS + 320) {
        int i = (blk - CAST_BLKS - 256) * 256 + tid;  // [0, 16384)
        int kk = i & 127, n = i >> 7;
        Wt3[n * 128 + kk] = f2bf(l1W[kk * 128 + n]);
    } else {
        if (tid < 128) {
            bs1[tid] = b1[tid] + b1[128 + tid] + b1[256 + tid] + b1[384 + tid];
            bs2[tid] = b2[tid] + b2[128 + tid] + b2[256 + tid] + b2[384 + tid];
        }
        bnsum[tid] = 0.f;  // 256 floats
    }
}

// ---------------- pass A: bin edges into (chunk, range) fragment windows ----------------
// packed = src | dstlocal<<16 (src<50000 fits 16 bits, dstlocal 9 bits)
__global__ __launch_bounds__(256) void k_bin(const int* __restrict__ ei,
                                             int* __restrict__ frag,
                                             int* __restrict__ cntg) {
    int c = blockIdx.x, r = blockIdx.y;
    const int* srcp = ei + r * 2 * NE;
    const int* dstp = srcp + NE;
    __shared__ int bins[NRANGE * FCAP];  // 37.6 KB
    __shared__ int cnt[NRANGE];
    int tid = threadIdx.x;
    for (int i = tid; i < NRANGE; i += 256) cnt[i] = 0;
    __syncthreads();
    int e0 = c * CH, e1 = min(e0 + CH, NE);
    for (int e = e0 + tid; e < e1; e += 256) {
        int d = dstp[e];
        int s = srcp[e];
        int q = d >> 9;
        int pos = atomicAdd(&cnt[q], 1);
        if (pos < FCAP) bins[q * FCAP + pos] = s | ((d & 511) << 16);
    }
    __syncthreads();
    int w = tid >> 6, lane = tid & 63;
    for (int q = w; q < NRANGE; q += 4) {
        int k = min(cnt[q], FCAP);
        int gbase = ((r * NRANGE + q) * NCH + c) * FCAP;
        for (int i = lane; i < k; i += 64) frag[gbase + i] = bins[q * FCAP + i];
    }
    for (int q = tid; q < NRANGE; q += 256) cntg[(r * NRANGE + q) * NCH + c] = min(cnt[q], FCAP);
}

// ---------------- pass B: per (range, rel) counting-sort into CSR ----------------
__global__ __launch_bounds__(512) void k_sortb(const int* __restrict__ frag,
                                               const int* __restrict__ cntg,
                                               unsigned short* __restrict__ csr,
                                               int* __restrict__ rstart,
                                               int* __restrict__ rend,
                                               float* __restrict__ dinv) {
    int q = blockIdx.x, r = blockIdx.y;
    int blk = r * NRANGE + q;
    int n0 = q * RSZ;
    int nrows = min(RSZ, NN - n0);
    __shared__ int cnts[NCH], cbase[NCH];
    __shared__ int stage[BCAP];          // 24 KB
    __shared__ unsigned short csr_s[BCAP];
    __shared__ int hist[RSZ], off[RSZ], cnt2[RSZ];
    int tid = threadIdx.x;
    hist[tid] = 0;
    cnt2[tid] = 0;
    if (tid < NCH) cnts[tid] = cntg[blk * NCH + tid];
    __syncthreads();
    // exclusive scan of 128 chunk counts
    if (tid < NCH) cbase[tid] = cnts[tid];
    __syncthreads();
    for (int d = 1; d < NCH; d <<= 1) {
        int t = 0;
        if (tid < NCH && tid >= d) t = cbase[tid - d];
        __syncthreads();
        if (tid < NCH) cbase[tid] += t;
        __syncthreads();
    }
    if (tid < NCH) cbase[tid] -= cnts[tid];
    __syncthreads();
    int tot = cbase[NCH - 1] + cnts[NCH - 1];
    // parallel gather of all 128 fragment windows (4 threads per chunk)
    {
        int g = tid >> 2, l = tid & 3;
        int k = cnts[g], cb = cbase[g];
        int gbase = (blk * NCH + g) * FCAP;
        for (int i = l; i < k; i += 4)
            if (cb + i < BCAP) stage[cb + i] = frag[gbase + i];
    }
    __syncthreads();
    if (tot > BCAP) tot = BCAP;
    // histogram over dst-local
    for (int i = tid; i < tot; i += 512) atomicAdd(&hist[(stage[i] >> 16) & 511], 1);
    __syncthreads();
    int h = hist[tid];
    if (tid < nrows) dinv[r * NN + n0 + tid] = rsqrtf((float)(h + 1));  // +1 self loop
    // inclusive scan -> exclusive offsets
    off[tid] = h;
    __syncthreads();
    for (int d = 1; d < RSZ; d <<= 1) {
        int t = (tid >= d) ? off[tid - d] : 0;
        __syncthreads();
        off[tid] += t;
        __syncthreads();
    }
    int excl = off[tid] - h;
    __syncthreads();
    off[tid] = excl;
    int base = blk * BCAP;
    if (tid < nrows) {
        rstart[r * NN + n0 + tid] = base + excl;
        rend[r * NN + n0 + tid] = base + excl + h;
    }
    __syncthreads();
    // counting-sort into LDS
    for (int i = tid; i < tot; i += 512) {
        int v = stage[i];
        int dl = (v >> 16) & 511;
        int p = atomicAdd(&cnt2[dl], 1);
        csr_s[off[dl] + p] = (unsigned short)(v & 0xFFFF);
    }
    __syncthreads();
    // coalesced block-private write-out
    for (int i = tid; i < tot; i += 512) csr[base + i] = csr_s[i];
}

// ---------------- per-node gather aggregation, 4 relation streams interleaved ----------------
// Acat[n][r*128+c] = dinv_r[n] * ( sum_{src->n} in[src][c]*dinv_r[src] + in[n][c]*dinv_r[n] )
// One wave per node. Branch-free inner loop: exhausted streams re-read their last edge
// (L1-hot) with weight cndmask'd to 0, so all 12 loads/iter batch in one basic block.
__global__ __launch_bounds__(256) void k_agg(const unsigned short* __restrict__ in,  // bf16 [NN][128]
                                             const unsigned short* __restrict__ csr,
                                             const int* __restrict__ rstart,
                                             const int* __restrict__ rend,
                                             const float* __restrict__ dinv,         // [NREL][NN]
                                             unsigned short* __restrict__ Acat) {    // bf16 [NN][512]
    int wave = threadIdx.x >> 6, lane = threadIdx.x & 63;
    int n = blockIdx.x * 4 + wave;
    if (n >= NN) return;
    const ushort2* in2 = (const ushort2*)in;
    int e0 = rstart[0 * NN + n], E0 = rend[0 * NN + n];
    int e1 = rstart[1 * NN + n], E1 = rend[1 * NN + n];
    int e2 = rstart[2 * NN + n], E2 = rend[2 * NN + n];
    int e3 = rstart[3 * NN + n], E3 = rend[3 * NN + n];
    int L0 = max(E0 - 1, 0), L1 = max(E1 - 1, 0);
    int L2 = max(E2 - 1, 0), L3 = max(E3 - 1, 0);
    float ax0 = 0.f, ay0 = 0.f, ax1 = 0.f, ay1 = 0.f;
    float ax2 = 0.f, ay2 = 0.f, ax3 = 0.f, ay3 = 0.f;
    while ((e0 < E0) | (e1 < E1) | (e2 < E2) | (e3 < E3)) {
        bool a0 = e0 < E0, a1 = e1 < E1, a2 = e2 < E2, a3 = e3 < E3;
        int i0 = a0 ? e0 : L0;
        int i1 = a1 ? e1 : L1;
        int i2 = a2 ? e2 : L2;
        int i3 = a3 ? e3 : L3;
        int s0 = csr[i0], s1 = csr[i1], s2 = csr[i2], s3 = csr[i3];
        float w0 = a0 ? dinv[0 * NN + s0] : 0.f;
        float w1 = a1 ? dinv[1 * NN + s1] : 0.f;
        float w2 = a2 ? dinv[2 * NN + s2] : 0.f;
        float w3 = a3 ? dinv[3 * NN + s3] : 0.f;
        ushort2 u0 = in2[s0 * 64 + lane];
        ushort2 u1 = in2[s1 * 64 + lane];
        ushort2 u2 = in2[s2 * 64 + lane];
        ushort2 u3 = in2[s3 * 64 + lane];
        ax0 = fmaf(bf2f(u0.x), w0, ax0); ay0 = fmaf(bf2f(u0.y), w0, ay0);
        ax1 = fmaf(bf2f(u1.x), w1, ax1); ay1 = fmaf(bf2f(u1.y), w1, ay1);
        ax2 = fmaf(bf2f(u2.x), w2, ax2); ay2 = fmaf(bf2f(u2.y), w2, ay2);
        ax3 = fmaf(bf2f(u3.x), w3, ax3); ay3 = fmaf(bf2f(u3.y), w3, ay3);
        e0 += a0; e1 += a1; e2 += a2; e3 += a3;
    }
    ushort2 us = in2[n * 64 + lane];
    float sx = bf2f(us.x), sy = bf2f(us.y);
    float wn0 = dinv[0 * NN + n], wn1 = dinv[1 * NN + n];
    float wn2 = dinv[2 * NN + n], wn3 = dinv[3 * NN + n];
    unsigned short* orow = Acat + (size_t)n * 512 + 2 * lane;
    ushort2 o;
    o.x = f2bf(wn0 * fmaf(sx, wn0, ax0)); o.y = f2bf(wn0 * fmaf(sy, wn0, ay0));
    *(ushort2*)(orow + 0) = o;
    o.x = f2bf(wn1 * fmaf(sx, wn1, ax1)); o.y = f2bf(wn1 * fmaf(sy, wn1, ay1));
    *(ushort2*)(orow + 128) = o;
    o.x = f2bf(wn2 * fmaf(sx, wn2, ax2)); o.y = f2bf(wn2 * fmaf(sy, wn2, ay2));
    *(ushort2*)(orow + 256) = o;
    o.x = f2bf(wn3 * fmaf(sx, wn3, ax3)); o.y = f2bf(wn3 * fmaf(sy, wn3, ay3));
    *(ushort2*)(orow + 384) = o;
}

// ---------------- MFMA GEMM: C[NN][128] = relu(A[NN][K] @ W[K][128] + bias) (bf16 in/out) ----------------
template <int K, bool STATS>
__global__ __launch_bounds__(256) void k_mm(const unsigned short* __restrict__ A,
                                            const unsigned short* __restrict__ Bt,
                                            const float* __restrict__ bias,
                                            unsigned short* __restrict__ C,
                                            float* __restrict__ bnsum) {
    int tid = threadIdx.x;
    int w = tid >> 6, lane = tid & 63;
    int ln = lane & 15, quad = lane >> 4;
    int mwave = blockIdx.x * 256 + w * 64;

    f32x4 acc[4][8];
#pragma unroll
    for (int a = 0; a < 4; a++)
#pragma unroll
        for (int b = 0; b < 8; b++) acc[a][b] = (f32x4){0.f, 0.f, 0.f, 0.f};

    size_t arow[4];
#pragma unroll
    for (int mf = 0; mf < 4; mf++) {
        int m = mwave + mf * 16 + ln;
        arow[mf] = (size_t)min(m, NN - 1) * K;  // clamp; garbage rows guarded at store
    }
    size_t brow[8];
#pragma unroll
    for (int nf = 0; nf < 8; nf++) brow[nf] = (size_t)(nf * 16 + ln) * K;

    for (int k0 = 0; k0 < K; k0 += 32) {
        int kof = k0 + quad * 8;
        short8 af[4], bf[8];
#pragma unroll
        for (int mf = 0; mf < 4; mf++) af[mf] = *(const short8*)(A + arow[mf] + kof);
#pragma unroll
        for (int nf = 0; nf < 8; nf++) bf[nf] = *(const short8*)(Bt + brow[nf] + kof);
#pragma unroll
        for (int mf = 0; mf < 4; mf++)
#pragma unroll
            for (int nf = 0; nf < 8; nf++)
                acc[mf][nf] = __builtin_amdgcn_mfma_f32_16x16x32_bf16(af[mf], bf[nf], acc[mf][nf], 0, 0, 0);
    }

    float bs[8];
#pragma unroll
    for (int nf = 0; nf < 8; nf++) bs[nf] = bias[nf * 16 + ln];
    float sn[8], qn[8];
#pragma unroll
    for (int nf = 0; nf < 8; nf++) { sn[nf] = 0.f; qn[nf] = 0.f; }

#pragma unroll
    for (int mf = 0; mf < 4; mf++)
#pragma unroll
        for (int nf = 0; nf < 8; nf++)
#pragma unroll
            for (int rg = 0; rg < 4; rg++) {
                int m = mwave + mf * 16 + quad * 4 + rg;
                if (m < NN) {
                    float v = fmaxf(acc[mf][nf][rg] + bs[nf], 0.f);
                    if (STATS) { sn[nf] += v; qn[nf] += v * v; }
                    C[(size_t)m * 128 + nf * 16 + ln] = f2bf(v);
                }
            }

    if (STATS) {
#pragma unroll
        for (int nf = 0; nf < 8; nf++) {
            float s = sn[nf], q = qn[nf];
            s += __shfl_xor(s, 16); s += __shfl_xor(s, 32);
            q += __shfl_xor(q, 16); q += __shfl_xor(q, 32);
            if (quad == 0) {
                unsafeAtomicAdd(&bnsum[nf * 16 + ln], s);
                unsafeAtomicAdd(&bnsum[128 + nf * 16 + ln], q);
            }
        }
    }
}

__global__ __launch_bounds__(128) void k_bn_final(const float* __restrict__ sums,
                                                  const float* __restrict__ gamma,
                                                  const float* __restrict__ beta,
                                                  float* __restrict__ bnp) {
    int c = threadIdx.x;
    if (c < D) {
        float mean = sums[c] / (float)NN;
        float var = sums[D + c] / (float)NN - mean * mean;
        float sc = gamma[c] * rsqrtf(var + BN_EPS);
        bnp[c] = sc;
        bnp[D + c] = beta[c] - mean * sc;
    }
}

// ---------------- final: out = relu(BN(R2) @ l1W + l1b) @ l2W + l2b ----------------
__global__ __launch_bounds__(256) void k_final(const unsigned short* __restrict__ R2,
                                               const float* __restrict__ bnp,
                                               const unsigned short* __restrict__ Wt3,
                                               const float* __restrict__ l1b,
                                               const float* __restrict__ l2W,
                                               const float* __restrict__ l2b,
                                               float* __restrict__ out) {
    int tid = threadIdx.x;
    int w = tid >> 6, lane = tid & 63;
    int ln = lane & 15, quad = lane >> 4;
    int mwave = blockIdx.x * 256 + w * 64;

    f32x4 acc[4][8];
#pragma unroll
    for (int a = 0; a < 4; a++)
#pragma unroll
        for (int b = 0; b < 8; b++) acc[a][b] = (f32x4){0.f, 0.f, 0.f, 0.f};

    size_t arow[4];
#pragma unroll
    for (int mf = 0; mf < 4; mf++) {
        int m = mwave + mf * 16 + ln;
        arow[mf] = (size_t)min(m, NN - 1) * 128;
    }
    size_t brow[8];
#pragma unroll
    for (int nf = 0; nf < 8; nf++) brow[nf] = (size_t)(nf * 16 + ln) * 128;

    for (int k0 = 0; k0 < 128; k0 += 32) {
        int kof = k0 + quad * 8;
        float4 scA = *(const float4*)(bnp + kof);
        float4 scB = *(const float4*)(bnp + kof + 4);
        float4 shA = *(const float4*)(bnp + 128 + kof);
        float4 shB = *(const float4*)(bnp + 128 + kof + 4);
        float scv[8] = {scA.x, scA.y, scA.z, scA.w, scB.x, scB.y, scB.z, scB.w};
        float shv[8] = {shA.x, shA.y, shA.z, shA.w, shB.x, shB.y, shB.z, shB.w};
        short8 af[4], bf[8];
#pragma unroll
        for (int mf = 0; mf < 4; mf++) {
            short8 rv = *(const short8*)(R2 + arow[mf] + kof);
            unsigned short ab[8];
#pragma unroll
            for (int j = 0; j < 8; j++)
                ab[j] = f2bf(bf2f((unsigned short)rv[j]) * scv[j] + shv[j]);
            af[mf] = *(short8*)ab;
        }
#pragma unroll
        for (int nf = 0; nf < 8; nf++) bf[nf] = *(const short8*)(Wt3 + brow[nf] + kof);
#pragma unroll
        for (int mf = 0; mf < 4; mf++)
#pragma unroll
            for (int nf = 0; nf < 8; nf++)
                acc[mf][nf] = __builtin_amdgcn_mfma_f32_16x16x32_bf16(af[mf], bf[nf], acc[mf][nf], 0, 0, 0);
    }

    float b1v[8], w0[8], w1[8];
#pragma unroll
    for (int nf = 0; nf < 8; nf++) {
        int n = nf * 16 + ln;
        b1v[nf] = l1b[n];
        w0[nf] = l2W[n * 2];
        w1[nf] = l2W[n * 2 + 1];
    }
    float ob0 = l2b[0], ob1 = l2b[1];
#pragma unroll
    for (int mf = 0; mf < 4; mf++)
#pragma unroll
        for (int rg = 0; rg < 4; rg++) {
            float p0 = 0.f, p1 = 0.f;
#pragma unroll
            for (int nf = 0; nf < 8; nf++) {
                float y = fmaxf(acc[mf][nf][rg] + b1v[nf], 0.f);
                p0 += y * w0[nf];
                p1 += y * w1[nf];
            }
            p0 += __shfl_xor(p0, 1); p0 += __shfl_xor(p0, 2);
            p0 += __shfl_xor(p0, 4); p0 += __shfl_xor(p0, 8);
            p1 += __shfl_xor(p1, 1); p1 += __shfl_xor(p1, 2);
            p1 += __shfl_xor(p1, 4); p1 += __shfl_xor(p1, 8);
            int m = mwave + mf * 16 + quad * 4 + rg;
            if (ln == 0 && m < NN) {
                out[(size_t)m * 2 + 0] = p0 + ob0;
                out[(size_t)m * 2 + 1] = p1 + ob1;
            }
        }
}

extern "C" void kernel_launch(void* const* d_in, const int* in_sizes, int n_in,
                              void* d_out, int out_size, void* d_ws, size_t ws_size,
                              hipStream_t stream) {
    const float* x = (const float*)d_in[0];
    const int* ei = (const int*)d_in[1];
    const float* W1 = (const float*)d_in[2];
    const float* b1 = (const float*)d_in[3];
    const float* W2 = (const float*)d_in[4];
    const float* b2 = (const float*)d_in[5];
    const float* gamma = (const float*)d_in[6];
    const float* beta = (const float*)d_in[7];
    const float* l1W = (const float*)d_in[8];
    const float* l1b = (const float*)d_in[9];
    const float* l2W = (const float*)d_in[10];
    const float* l2b = (const float*)d_in[11];
    float* out = (float*)d_out;

    char* ws = (char*)d_ws;
    size_t off = 0;
    auto alloc = [&](size_t bytes) {
        void* p = ws + off;
        off += (bytes + 255) & ~(size_t)255;
        return p;
    };
    float* dinv = (float*)alloc((size_t)NREL * NN * sizeof(float));
    int* rstart = (int*)alloc((size_t)NREL * NN * sizeof(int));
    int* rend = (int*)alloc((size_t)NREL * NN * sizeof(int));
    unsigned short* csr = (unsigned short*)alloc((size_t)NBK * BCAP * 2);            // 4.8 MB
    unsigned short* xb = (unsigned short*)alloc((size_t)NN * D * 2);                 // 12.8 MB
    unsigned short* Acat = (unsigned short*)alloc((size_t)NN * 512 * 2);             // 51.2 MB
    unsigned short* h1b = (unsigned short*)alloc((size_t)NN * D * 2);                // 12.8 MB
    unsigned short* R2b = (unsigned short*)alloc((size_t)NN * D * 2);                // 12.8 MB
    unsigned short* Wt1 = (unsigned short*)alloc(128 * 512 * 2);
    unsigned short* Wt2 = (unsigned short*)alloc(128 * 512 * 2);
    unsigned short* Wt3 = (unsigned short*)alloc(128 * 128 * 2);
    float* bs1 = (float*)alloc(128 * sizeof(float));
    float* bs2 = (float*)alloc(128 * sizeof(float));
    float* bnsum = (float*)alloc(256 * sizeof(float));
    float* bnp = (float*)alloc(256 * sizeof(float));

    // frag/cntg alias Acat's storage (dead until k_agg writes it, after k_sortb completes)
    int* frag = (int*)Acat;                                       // 19.3 MB
    int* cntg = frag + (size_t)NREL * NRANGE * NCH * FCAP;        // 0.2 MB

    k_pre<<<CAST_BLKS + 321, 256, 0, stream>>>(x, W1, W2, l1W, b1, b2, xb, Wt1, Wt2, Wt3,
                                               bs1, bs2, bnsum);
    dim3 bgrid(NCH, NREL);
    k_bin<<<bgrid, 256, 0, stream>>>(ei, frag, cntg);
    dim3 sgrid(NRANGE, NREL);
    k_sortb<<<sgrid, 512, 0, stream>>>(frag, cntg, csr, rstart, rend, dinv);

    int agrid = (NN + 3) / 4;
    // layer 1: aggregate x (all 4 relations) -> Acat, then one K=512 GEMM
    k_agg<<<agrid, 256, 0, stream>>>(xb, csr, rstart, rend, dinv, Acat);
    k_mm<512, false><<<(NN + 255) / 256, 256, 0, stream>>>(Acat, Wt1, bs1, h1b, nullptr);
    // layer 2
    k_agg<<<agrid, 256, 0, stream>>>(h1b, csr, rstart, rend, dinv, Acat);
    k_mm<512, true><<<(NN + 255) / 256, 256, 0, stream>>>(Acat, Wt2, bs2, R2b, bnsum);
    // BN params + fused MLP head
    k_bn_final<<<1, 128, 0, stream>>>(bnsum, gamma, beta, bnp);
    k_final<<<(NN + 255) / 256, 256, 0, stream>>>(R2b, bnp, Wt3, l1b, l2W, l2b, out);
}

// Round 7
// 431.187 us; speedup vs baseline: 1.1589x; 1.1589x over previous
//
#include <hip/hip_runtime.h>
#include <math.h>

#define NN 50000
#define NE 500000
#define NREL 4
#define D 128
#define RSZ 512                 // dst-range size (one bin)
#define NRANGE 98               // ceil(NN/512)
#define NBK (NREL * NRANGE)     // 392 sort blocks
#define BCAP 6144               // per-(range,rel) csr capacity (mean 5120, +14 sigma)
#define NCH 128                 // edge chunks per relation
#define CH 3907                 // edges per chunk (128*3907 >= 500000)
#define FCAP 96                 // frag capacity per (chunk,bin): mean 40, +9 sigma
#define CAST_BLKS 6250          // NN*D/4/256
static constexpr float BN_EPS = 1e-5f;

typedef __attribute__((ext_vector_type(8))) short short8;
typedef __attribute__((ext_vector_type(4))) float f32x4;

__device__ __forceinline__ float bf2f(unsigned short u) {
    return __uint_as_float(((unsigned)u) << 16);
}
__device__ __forceinline__ unsigned short f2bf(float f) {  // RTNE
    unsigned x = __float_as_uint(f);
    return (unsigned short)((x + 0x7FFFu + ((x >> 16) & 1u)) >> 16);
}

// ---------------- fused prologue: cast x->bf16, weight transpose+cast, bias sums, bnsum zero ----
__global__ __launch_bounds__(256) void k_pre(const float* __restrict__ x,
                                             const float* __restrict__ W1, const float* __restrict__ W2,
                                             const float* __restrict__ l1W, const float* __restrict__ b1,
                                             const float* __restrict__ b2,
                                             unsigned short* __restrict__ xb,
                                             unsigned short* __restrict__ Wt1,
                                             unsigned short* __restrict__ Wt2,
                                             unsigned short* __restrict__ Wt3,
                                             float* __restrict__ bs1, float* __restrict__ bs2,
                                             float* __restrict__ bnsum) {
    int blk = blockIdx.x, tid = threadIdx.x;
    if (blk < CAST_BLKS) {
        int i = blk * 256 + tid;
        float4 v = *(const float4*)(x + (size_t)i * 4);
        unsigned short u[4] = {f2bf(v.x), f2bf(v.y), f2bf(v.z), f2bf(v.w)};
        *(ushort4*)(xb + (size_t)i * 4) = *(ushort4*)u;
    } else if (blk < CAST_BLKS + 256) {
        int i = (blk - CAST_BLKS) * 256 + tid;  // [0, 65536)
        int kk = i & 511, n = i >> 9;           // coalesced stores along kk
        Wt1[n * 512 + kk] = f2bf(W1[kk * 128 + n]);
        Wt2[n * 512 + kk] = f2bf(W2[kk * 128 + n]);
    } else if (blk < CAST_BLKS + 320) {
        int i = (blk - CAST_BLKS - 256) * 256 + tid;  // [0, 16384)
        int kk = i & 127, n = i >> 7;
        Wt3[n * 128 + kk] = f2bf(l1W[kk * 128 + n]);
    } else {
        if (tid < 128) {
            bs1[tid] = b1[tid] + b1[128 + tid] + b1[256 + tid] + b1[384 + tid];
            bs2[tid] = b2[tid] + b2[128 + tid] + b2[256 + tid] + b2[384 + tid];
        }
        bnsum[tid] = 0.f;  // 256 floats
    }
}

// ---------------- pass A: bin edges into (chunk, range) fragment windows ----------------
// packed = src | dstlocal<<16 (src<50000 fits 16 bits, dstlocal 9 bits)
__global__ __launch_bounds__(256) void k_bin(const int* __restrict__ ei,
                                             int* __restrict__ frag,
                                             int* __restrict__ cntg) {
    int c = blockIdx.x, r = blockIdx.y;
    const int* srcp = ei + r * 2 * NE;
    const int* dstp = srcp + NE;
    __shared__ int bins[NRANGE * FCAP];  // 37.6 KB
    __shared__ int cnt[NRANGE];
    int tid = threadIdx.x;
    for (int i = tid; i < NRANGE; i += 256) cnt[i] = 0;
    __syncthreads();
    int e0 = c * CH, e1 = min(e0 + CH, NE);
    for (int e = e0 + tid; e < e1; e += 256) {
        int d = dstp[e];
        int s = srcp[e];
        int q = d >> 9;
        int pos = atomicAdd(&cnt[q], 1);
        if (pos < FCAP) bins[q * FCAP + pos] = s | ((d & 511) << 16);
    }
    __syncthreads();
    int w = tid >> 6, lane = tid & 63;
    for (int q = w; q < NRANGE; q += 4) {
        int k = min(cnt[q], FCAP);
        int gbase = ((r * NRANGE + q) * NCH + c) * FCAP;
        for (int i = lane; i < k; i += 64) frag[gbase + i] = bins[q * FCAP + i];
    }
    for (int q = tid; q < NRANGE; q += 256) cntg[(r * NRANGE + q) * NCH + c] = min(cnt[q], FCAP);
}

// ---------------- pass B: per (range, rel) counting-sort into CSR ----------------
__global__ __launch_bounds__(512) void k_sortb(const int* __restrict__ frag,
                                               const int* __restrict__ cntg,
                                               unsigned short* __restrict__ csr,
                                               int* __restrict__ rstart,
                                               int* __restrict__ rend,
                                               float* __restrict__ dinv) {
    int q = blockIdx.x, r = blockIdx.y;
    int blk = r * NRANGE + q;
    int n0 = q * RSZ;
    int nrows = min(RSZ, NN - n0);
    __shared__ int cnts[NCH], cbase[NCH];
    __shared__ int stage[BCAP];          // 24 KB
    __shared__ unsigned short csr_s[BCAP];
    __shared__ int hist[RSZ], off[RSZ], cnt2[RSZ];
    int tid = threadIdx.x;
    hist[tid] = 0;
    cnt2[tid] = 0;
    if (tid < NCH) cnts[tid] = cntg[blk * NCH + tid];
    __syncthreads();
    // exclusive scan of 128 chunk counts
    if (tid < NCH) cbase[tid] = cnts[tid];
    __syncthreads();
    for (int d = 1; d < NCH; d <<= 1) {
        int t = 0;
        if (tid < NCH && tid >= d) t = cbase[tid - d];
        __syncthreads();
        if (tid < NCH) cbase[tid] += t;
        __syncthreads();
    }
    if (tid < NCH) cbase[tid] -= cnts[tid];
    __syncthreads();
    int tot = cbase[NCH - 1] + cnts[NCH - 1];
    // parallel gather of all 128 fragment windows (4 threads per chunk)
    {
        int g = tid >> 2, l = tid & 3;
        int k = cnts[g], cb = cbase[g];
        int gbase = (blk * NCH + g) * FCAP;
        for (int i = l; i < k; i += 4)
            if (cb + i < BCAP) stage[cb + i] = frag[gbase + i];
    }
    __syncthreads();
    if (tot > BCAP) tot = BCAP;
    // histogram over dst-local
    for (int i = tid; i < tot; i += 512) atomicAdd(&hist[(stage[i] >> 16) & 511], 1);
    __syncthreads();
    int h = hist[tid];
    if (tid < nrows) dinv[r * NN + n0 + tid] = rsqrtf((float)(h + 1));  // +1 self loop
    // inclusive scan -> exclusive offsets
    off[tid] = h;
    __syncthreads();
    for (int d = 1; d < RSZ; d <<= 1) {
        int t = (tid >= d) ? off[tid - d] : 0;
        __syncthreads();
        off[tid] += t;
        __syncthreads();
    }
    int excl = off[tid] - h;
    __syncthreads();
    off[tid] = excl;
    int base = blk * BCAP;
    if (tid < nrows) {
        rstart[r * NN + n0 + tid] = base + excl;
        rend[r * NN + n0 + tid] = base + excl + h;
    }
    __syncthreads();
    // counting-sort into LDS
    for (int i = tid; i < tot; i += 512) {
        int v = stage[i];
        int dl = (v >> 16) & 511;
        int p = atomicAdd(&cnt2[dl], 1);
        csr_s[off[dl] + p] = (unsigned short)(v & 0xFFFF);
    }
    __syncthreads();
    // coalesced block-private write-out
    for (int i = tid; i < tot; i += 512) csr[base + i] = csr_s[i];
}

// ---------------- per-(node,relation) gather aggregation, lane-split ----------------
// Wave handles one (node, relation). Lane l: half=l>>5 (edge parity), c=l&31 (4-col group).
// Each row-load instruction fetches 2 rows (2 x 256B); per-edge VALU ~halved vs 2-col/lane.
__global__ __launch_bounds__(256) void k_agg(const unsigned short* __restrict__ in,  // bf16 [NN][128]
                                             const unsigned short* __restrict__ csr,
                                             const int* __restrict__ rstart,
                                             const int* __restrict__ rend,
                                             const float* __restrict__ dinv,         // [NREL][NN]
                                             unsigned short* __restrict__ Acat) {    // bf16 [NN][512]
    int r = blockIdx.y;
    int wave = threadIdx.x >> 6, lane = threadIdx.x & 63;
    int n = blockIdx.x * 4 + wave;
    if (n >= NN) return;
    const float* dv = dinv + r * NN;
    int start = rstart[r * NN + n], end = rend[r * NN + n];
    int half = lane >> 5;   // 0/1: alternate edges
    int c = lane & 31;      // 4-column group
    const ushort4* in4 = (const ushort4*)in;  // row stride 32
    float a0 = 0.f, a1 = 0.f, a2 = 0.f, a3 = 0.f;
    int e = start + half;
    // main: 2 edges per half per iteration (4 edges/wave-iter, 4 row-loads in flight)
    for (; e + 2 < end; e += 4) {
        int s0 = csr[e], s1 = csr[e + 2];
        float w0 = dv[s0], w1 = dv[s1];
        ushort4 u0 = in4[s0 * 32 + c];
        ushort4 u1 = in4[s1 * 32 + c];
        a0 = fmaf(bf2f(u0.x), w0, a0); a1 = fmaf(bf2f(u0.y), w0, a1);
        a2 = fmaf(bf2f(u0.z), w0, a2); a3 = fmaf(bf2f(u0.w), w0, a3);
        a0 = fmaf(bf2f(u1.x), w1, a0); a1 = fmaf(bf2f(u1.y), w1, a1);
        a2 = fmaf(bf2f(u1.z), w1, a2); a3 = fmaf(bf2f(u1.w), w1, a3);
    }
    // tail: at most 1 more edge for this half
    if (e < end) {
        int s = csr[e];
        float w = dv[s];
        ushort4 u = in4[s * 32 + c];
        a0 = fmaf(bf2f(u.x), w, a0); a1 = fmaf(bf2f(u.y), w, a1);
        a2 = fmaf(bf2f(u.z), w, a2); a3 = fmaf(bf2f(u.w), w, a3);
    }
    // combine halves
    a0 += __shfl_xor(a0, 32); a1 += __shfl_xor(a1, 32);
    a2 += __shfl_xor(a2, 32); a3 += __shfl_xor(a3, 32);
    // self loop + scale + write (lanes 0-31 only)
    float wn = dv[n];
    ushort4 us = in4[n * 32 + c];
    unsigned short ob[4];
    ob[0] = f2bf(wn * fmaf(bf2f(us.x), wn, a0));
    ob[1] = f2bf(wn * fmaf(bf2f(us.y), wn, a1));
    ob[2] = f2bf(wn * fmaf(bf2f(us.z), wn, a2));
    ob[3] = f2bf(wn * fmaf(bf2f(us.w), wn, a3));
    if (half == 0)
        *(ushort4*)(Acat + (size_t)n * 512 + r * 128 + 4 * c) = *(ushort4*)ob;
}

// ---------------- MFMA GEMM: C[NN][128] = relu(A[NN][K] @ W[K][128] + bias) (bf16 in/out) ----------------
template <int K, bool STATS>
__global__ __launch_bounds__(256) void k_mm(const unsigned short* __restrict__ A,
                                            const unsigned short* __restrict__ Bt,
                                            const float* __restrict__ bias,
                                            unsigned short* __restrict__ C,
                                            float* __restrict__ bnsum) {
    int tid = threadIdx.x;
    int w = tid >> 6, lane = tid & 63;
    int ln = lane & 15, quad = lane >> 4;
    int mwave = blockIdx.x * 256 + w * 64;

    f32x4 acc[4][8];
#pragma unroll
    for (int a = 0; a < 4; a++)
#pragma unroll
        for (int b = 0; b < 8; b++) acc[a][b] = (f32x4){0.f, 0.f, 0.f, 0.f};

    size_t arow[4];
#pragma unroll
    for (int mf = 0; mf < 4; mf++) {
        int m = mwave + mf * 16 + ln;
        arow[mf] = (size_t)min(m, NN - 1) * K;  // clamp; garbage rows guarded at store
    }
    size_t brow[8];
#pragma unroll
    for (int nf = 0; nf < 8; nf++) brow[nf] = (size_t)(nf * 16 + ln) * K;

    for (int k0 = 0; k0 < K; k0 += 32) {
        int kof = k0 + quad * 8;
        short8 af[4], bf[8];
#pragma unroll
        for (int mf = 0; mf < 4; mf++) af[mf] = *(const short8*)(A + arow[mf] + kof);
#pragma unroll
        for (int nf = 0; nf < 8; nf++) bf[nf] = *(const short8*)(Bt + brow[nf] + kof);
#pragma unroll
        for (int mf = 0; mf < 4; mf++)
#pragma unroll
            for (int nf = 0; nf < 8; nf++)
                acc[mf][nf] = __builtin_amdgcn_mfma_f32_16x16x32_bf16(af[mf], bf[nf], acc[mf][nf], 0, 0, 0);
    }

    float bs[8];
#pragma unroll
    for (int nf = 0; nf < 8; nf++) bs[nf] = bias[nf * 16 + ln];
    float sn[8], qn[8];
#pragma unroll
    for (int nf = 0; nf < 8; nf++) { sn[nf] = 0.f; qn[nf] = 0.f; }

#pragma unroll
    for (int mf = 0; mf < 4; mf++)
#pragma unroll
        for (int nf = 0; nf < 8; nf++)
#pragma unroll
            for (int rg = 0; rg < 4; rg++) {
                int m = mwave + mf * 16 + quad * 4 + rg;
                if (m < NN) {
                    float v = fmaxf(acc[mf][nf][rg] + bs[nf], 0.f);
                    if (STATS) { sn[nf] += v; qn[nf] += v * v; }
                    C[(size_t)m * 128 + nf * 16 + ln] = f2bf(v);
                }
            }

    if (STATS) {
#pragma unroll
        for (int nf = 0; nf < 8; nf++) {
            float s = sn[nf], q = qn[nf];
            s += __shfl_xor(s, 16); s += __shfl_xor(s, 32);
            q += __shfl_xor(q, 16); q += __shfl_xor(q, 32);
            if (quad == 0) {
                unsafeAtomicAdd(&bnsum[nf * 16 + ln], s);
                unsafeAtomicAdd(&bnsum[128 + nf * 16 + ln], q);
            }
        }
    }
}

// ---------------- final: BN affine from bnsum + relu(BN(R2)@l1W+l1b)@l2W+l2b ----------------
__global__ __launch_bounds__(256) void k_final(const unsigned short* __restrict__ R2,
                                               const float* __restrict__ bnsum,
                                               const float* __restrict__ gamma,
                                               const float* __restrict__ beta,
                                               const unsigned short* __restrict__ Wt3,
                                               const float* __restrict__ l1b,
                                               const float* __restrict__ l2W,
                                               const float* __restrict__ l2b,
                                               float* __restrict__ out) {
    __shared__ float bnp_s[256];
    int tid = threadIdx.x;
    if (tid < 128) {
        float mean = bnsum[tid] / (float)NN;
        float var = bnsum[128 + tid] / (float)NN - mean * mean;
        float sc = gamma[tid] * rsqrtf(var + BN_EPS);
        bnp_s[tid] = sc;
        bnp_s[128 + tid] = beta[tid] - mean * sc;
    }
    __syncthreads();
    int w = tid >> 6, lane = tid & 63;
    int ln = lane & 15, quad = lane >> 4;
    int mwave = blockIdx.x * 256 + w * 64;

    f32x4 acc[4][8];
#pragma unroll
    for (int a = 0; a < 4; a++)
#pragma unroll
        for (int b = 0; b < 8; b++) acc[a][b] = (f32x4){0.f, 0.f, 0.f, 0.f};

    size_t arow[4];
#pragma unroll
    for (int mf = 0; mf < 4; mf++) {
        int m = mwave + mf * 16 + ln;
        arow[mf] = (size_t)min(m, NN - 1) * 128;
    }
    size_t brow[8];
#pragma unroll
    for (int nf = 0; nf < 8; nf++) brow[nf] = (size_t)(nf * 16 + ln) * 128;

    for (int k0 = 0; k0 < 128; k0 += 32) {
        int kof = k0 + quad * 8;
        float scv[8], shv[8];
#pragma unroll
        for (int j = 0; j < 8; j++) {
            scv[j] = bnp_s[kof + j];
            shv[j] = bnp_s[128 + kof + j];
        }
        short8 af[4], bf[8];
#pragma unroll
        for (int mf = 0; mf < 4; mf++) {
            short8 rv = *(const short8*)(R2 + arow[mf] + kof);
            unsigned short ab[8];
#pragma unroll
            for (int j = 0; j < 8; j++)
                ab[j] = f2bf(bf2f((unsigned short)rv[j]) * scv[j] + shv[j]);
            af[mf] = *(short8*)ab;
        }
#pragma unroll
        for (int nf = 0; nf < 8; nf++) bf[nf] = *(const short8*)(Wt3 + brow[nf] + kof);
#pragma unroll
        for (int mf = 0; mf < 4; mf++)
#pragma unroll
            for (int nf = 0; nf < 8; nf++)
                acc[mf][nf] = __builtin_amdgcn_mfma_f32_16x16x32_bf16(af[mf], bf[nf], acc[mf][nf], 0, 0, 0);
    }

    float b1v[8], w0[8], w1[8];
#pragma unroll
    for (int nf = 0; nf < 8; nf++) {
        int n = nf * 16 + ln;
        b1v[nf] = l1b[n];
        w0[nf] = l2W[n * 2];
        w1[nf] = l2W[n * 2 + 1];
    }
    float ob0 = l2b[0], ob1 = l2b[1];
#pragma unroll
    for (int mf = 0; mf < 4; mf++)
#pragma unroll
        for (int rg = 0; rg < 4; rg++) {
            float p0 = 0.f, p1 = 0.f;
#pragma unroll
            for (int nf = 0; nf < 8; nf++) {
                float y = fmaxf(acc[mf][nf][rg] + b1v[nf], 0.f);
                p0 += y * w0[nf];
                p1 += y * w1[nf];
            }
            p0 += __shfl_xor(p0, 1); p0 += __shfl_xor(p0, 2);
            p0 += __shfl_xor(p0, 4); p0 += __shfl_xor(p0, 8);
            p1 += __shfl_xor(p1, 1); p1 += __shfl_xor(p1, 2);
            p1 += __shfl_xor(p1, 4); p1 += __shfl_xor(p1, 8);
            int m = mwave + mf * 16 + quad * 4 + rg;
            if (ln == 0 && m < NN) {
                out[(size_t)m * 2 + 0] = p0 + ob0;
                out[(size_t)m * 2 + 1] = p1 + ob1;
            }
        }
}

extern "C" void kernel_launch(void* const* d_in, const int* in_sizes, int n_in,
                              void* d_out, int out_size, void* d_ws, size_t ws_size,
                              hipStream_t stream) {
    const float* x = (const float*)d_in[0];
    const int* ei = (const int*)d_in[1];
    const float* W1 = (const float*)d_in[2];
    const float* b1 = (const float*)d_in[3];
    const float* W2 = (const float*)d_in[4];
    const float* b2 = (const float*)d_in[5];
    const float* gamma = (const float*)d_in[6];
    const float* beta = (const float*)d_in[7];
    const float* l1W = (const float*)d_in[8];
    const float* l1b = (const float*)d_in[9];
    const float* l2W = (const float*)d_in[10];
    const float* l2b = (const float*)d_in[11];
    float* out = (float*)d_out;

    char* ws = (char*)d_ws;
    size_t off = 0;
    auto alloc = [&](size_t bytes) {
        void* p = ws + off;
        off += (bytes + 255) & ~(size_t)255;
        return p;
    };
    float* dinv = (float*)alloc((size_t)NREL * NN * sizeof(float));
    int* rstart = (int*)alloc((size_t)NREL * NN * sizeof(int));
    int* rend = (int*)alloc((size_t)NREL * NN * sizeof(int));
    unsigned short* csr = (unsigned short*)alloc((size_t)NBK * BCAP * 2);            // 4.8 MB
    unsigned short* xb = (unsigned short*)alloc((size_t)NN * D * 2);                 // 12.8 MB
    unsigned short* Acat = (unsigned short*)alloc((size_t)NN * 512 * 2);             // 51.2 MB
    unsigned short* h1b = (unsigned short*)alloc((size_t)NN * D * 2);                // 12.8 MB
    unsigned short* R2b = (unsigned short*)alloc((size_t)NN * D * 2);                // 12.8 MB
    unsigned short* Wt1 = (unsigned short*)alloc(128 * 512 * 2);
    unsigned short* Wt2 = (unsigned short*)alloc(128 * 512 * 2);
    unsigned short* Wt3 = (unsigned short*)alloc(128 * 128 * 2);
    float* bs1 = (float*)alloc(128 * sizeof(float));
    float* bs2 = (float*)alloc(128 * sizeof(float));
    float* bnsum = (float*)alloc(256 * sizeof(float));

    // frag/cntg alias Acat's storage (dead until k_agg writes it, after k_sortb completes)
    int* frag = (int*)Acat;                                       // 19.3 MB
    int* cntg = frag + (size_t)NREL * NRANGE * NCH * FCAP;        // 0.2 MB

    k_pre<<<CAST_BLKS + 321, 256, 0, stream>>>(x, W1, W2, l1W, b1, b2, xb, Wt1, Wt2, Wt3,
                                               bs1, bs2, bnsum);
    dim3 bgrid(NCH, NREL);
    k_bin<<<bgrid, 256, 0, stream>>>(ei, frag, cntg);
    dim3 sgrid(NRANGE, NREL);
    k_sortb<<<sgrid, 512, 0, stream>>>(frag, cntg, csr, rstart, rend, dinv);

    dim3 agrid((NN + 3) / 4, NREL);
    // layer 1: aggregate x per relation -> Acat (concat), then one K=512 GEMM
    k_agg<<<agrid, 256, 0, stream>>>(xb, csr, rstart, rend, dinv, Acat);
    k_mm<512, false><<<(NN + 255) / 256, 256, 0, stream>>>(Acat, Wt1, bs1, h1b, nullptr);
    // layer 2
    k_agg<<<agrid, 256, 0, stream>>>(h1b, csr, rstart, rend, dinv, Acat);
    k_mm<512, true><<<(NN + 255) / 256, 256, 0, stream>>>(Acat, Wt2, bs2, R2b, bnsum);
    // fused BN + MLP head
    k_final<<<(NN + 255) / 256, 256, 0, stream>>>(R2b, bnsum, gamma, beta, Wt3, l1b, l2W, l2b, out);
}